// Round 1
// baseline (3844.087 us; speedup 1.0000x reference)
//
#include <hip/hip_runtime.h>

#define T_STEPS 64
#define BATCH   256
#define IN_SZ   1024
#define HID     4096
#define BLK     512
#define GATES   12288   // 3*HID
#define GROW    1536    // 3*BLK, rows per diagonal block

using bf16x8  = __attribute__((ext_vector_type(8))) __bf16;
using floatx4 = __attribute__((ext_vector_type(4))) float;

__device__ __forceinline__ unsigned short f2bf(float f) {
    union { float f; unsigned int u; } v; v.f = f;
    unsigned int u = v.u;
    unsigned int r = (u + 0x7fffu + ((u >> 16) & 1u)) >> 16;
    return (unsigned short)r;
}

// ---- fp32 -> bf16 cast (vectorized x4) ----
__global__ __launch_bounds__(256) void cast_f32_bf16(
    const float* __restrict__ in, unsigned short* __restrict__ out, int n4)
{
    int i = blockIdx.x * 256 + threadIdx.x;
    if (i >= n4) return;
    float4 v = reinterpret_cast<const float4*>(in)[i];
    ushort4 o;
    o.x = f2bf(v.x); o.y = f2bf(v.y); o.z = f2bf(v.z); o.w = f2bf(v.w);
    reinterpret_cast<ushort4*>(out)[i] = o;
}

// ---- init h state (fp32 in d_out's h_T region) + bf16 copy ----
__global__ __launch_bounds__(256) void init_h(
    const float* __restrict__ h0, float* __restrict__ hT,
    unsigned short* __restrict__ hbf, int n)
{
    int i = blockIdx.x * 256 + threadIdx.x;
    if (i >= n) return;
    float v = h0[i];
    hT[i] = v;
    hbf[i] = f2bf(v);
}

// ---- per-step GEMMs: blocks [0,192) -> xg = x_t . Wi^T ; [192,384) -> hg = h . Wh^T (block-diag) ----
// MFMA orientation: A-operand = batch rows (m), B-operand = weight rows (n=gate j).
// A frag: lane holds A[m=lane&15][k=(lane>>4)*8 + j]; B frag same with n=lane&15.
// D frag: row(m) = (lane>>4)*4 + reg, col(n) = lane&15.
__global__ __launch_bounds__(256) void gemm_step(
    const unsigned short* __restrict__ xbf,   // (256,1024) for this t
    const unsigned short* __restrict__ hbf,   // (256,4096)
    const unsigned short* __restrict__ wi,    // (12288,1024)
    const unsigned short* __restrict__ wh,    // (12288,512) flat: row j = W_h[j/1536][j%1536][:]
    float* __restrict__ xgb,                  // (256,12288)
    float* __restrict__ hgb)                  // (256,12288)
{
    const int bx    = blockIdx.x;
    const bool is_hg = (bx >= 192);
    const int j0    = (is_hg ? (bx - 192) : bx) * 64;
    const int wave  = threadIdx.x >> 6;
    const int lane  = threadIdx.x & 63;
    const int q     = lane >> 4;
    const int l16   = lane & 15;
    const int m_base = wave * 64;   // 4 waves cover batch 0..255

    const unsigned short* A;
    const unsigned short* Bm;
    int lda, K;
    float* C;
    if (is_hg) {
        A   = hbf + (j0 / GROW) * BLK;   // h column slice for this diagonal block
        lda = HID; K = BLK;
        Bm  = wh + (size_t)j0 * BLK;
        C   = hgb;
    } else {
        A   = xbf;
        lda = IN_SZ; K = IN_SZ;
        Bm  = wi + (size_t)j0 * IN_SZ;
        C   = xgb;
    }
    const int ldb = K;

    floatx4 acc[4][4];
    #pragma unroll
    for (int mf = 0; mf < 4; mf++)
        #pragma unroll
        for (int nf = 0; nf < 4; nf++)
            acc[mf][nf] = floatx4{0.0f, 0.0f, 0.0f, 0.0f};

    const unsigned short* a_ptr[4];
    const unsigned short* b_ptr[4];
    #pragma unroll
    for (int mf = 0; mf < 4; mf++)
        a_ptr[mf] = A + (size_t)(m_base + mf * 16 + l16) * lda + q * 8;
    #pragma unroll
    for (int nf = 0; nf < 4; nf++)
        b_ptr[nf] = Bm + (size_t)(nf * 16 + l16) * ldb + q * 8;

    for (int k0 = 0; k0 < K; k0 += 32) {
        bf16x8 a[4], b[4];
        #pragma unroll
        for (int mf = 0; mf < 4; mf++)
            a[mf] = *reinterpret_cast<const bf16x8*>(a_ptr[mf] + k0);
        #pragma unroll
        for (int nf = 0; nf < 4; nf++)
            b[nf] = *reinterpret_cast<const bf16x8*>(b_ptr[nf] + k0);
        #pragma unroll
        for (int mf = 0; mf < 4; mf++)
            #pragma unroll
            for (int nf = 0; nf < 4; nf++)
                acc[mf][nf] = __builtin_amdgcn_mfma_f32_16x16x32_bf16(
                    a[mf], b[nf], acc[mf][nf], 0, 0, 0);
    }

    // Epilogue: C[(batch)*GATES + j], coalesced across l16 (16 consecutive floats)
    #pragma unroll
    for (int mf = 0; mf < 4; mf++) {
        const int brow0 = m_base + mf * 16 + q * 4;
        #pragma unroll
        for (int nf = 0; nf < 4; nf++) {
            const int col = j0 + nf * 16 + l16;
            #pragma unroll
            for (int r = 0; r < 4; r++)
                C[(size_t)(brow0 + r) * GATES + col] = acc[mf][nf][r];
        }
    }
}

// ---- pointwise GRU update ----
__global__ __launch_bounds__(256) void pointwise(
    const float* __restrict__ xgb, const float* __restrict__ hgb,
    const float* __restrict__ wib, const float* __restrict__ bh,
    float* __restrict__ hT, float* __restrict__ out,
    unsigned short* __restrict__ hbf)
{
    int gid = blockIdx.x * 256 + threadIdx.x;   // 0 .. 1048575
    int b = gid >> 12;
    int i = gid & 4095;
    size_t base = (size_t)b * GATES;

    float g_r  = (xgb[base + i]        + wib[i])        + (hgb[base + i]        + bh[i]);
    float g_z  = (xgb[base + HID + i]  + wib[HID + i])  + (hgb[base + HID + i]  + bh[HID + i]);
    float x_n  =  xgb[base + 2*HID + i] + wib[2*HID + i];
    float h_n  =  hgb[base + 2*HID + i] + bh[2*HID + i];

    float r = 1.0f / (1.0f + __expf(-g_r));
    float z = 1.0f / (1.0f + __expf(-g_z));
    float n = tanhf(x_n + r * h_n);

    size_t hi = (size_t)b * HID + i;
    float h_old = hT[hi];
    float h_new = (1.0f - z) * n + z * h_old;
    hT[hi]  = h_new;
    out[hi] = h_new;
    hbf[hi] = f2bf(h_new);
}

extern "C" void kernel_launch(void* const* d_in, const int* in_sizes, int n_in,
                              void* d_out, int out_size, void* d_ws, size_t ws_size,
                              hipStream_t stream)
{
    const float* x   = (const float*)d_in[0];   // (64,256,1024)
    const float* h0  = (const float*)d_in[1];   // (256,4096)
    const float* Wi  = (const float*)d_in[2];   // (12288,1024)
    const float* Wib = (const float*)d_in[3];   // (12288,)
    const float* Wh  = (const float*)d_in[4];   // (8,1536,512)
    const float* bh  = (const float*)d_in[5];   // (12288,)

    float* out = (float*)d_out;                          // (64,256,4096)
    float* hT  = out + (size_t)T_STEPS * BATCH * HID;    // (256,4096) — doubles as live h state

    // workspace layout (bf16 stored as ushort); ~86 MB total
    unsigned short* x_bf  = (unsigned short*)d_ws;                         // 64*256*1024
    unsigned short* wi_bf = x_bf  + (size_t)T_STEPS * BATCH * IN_SZ;       // 12288*1024
    unsigned short* wh_bf = wi_bf + (size_t)GATES * IN_SZ;                 // 12288*512
    unsigned short* h_bf  = wh_bf + (size_t)GATES * BLK;                   // 256*4096
    float* xgb = (float*)(h_bf + (size_t)BATCH * HID);                     // 256*12288
    float* hgb = xgb + (size_t)BATCH * GATES;                              // 256*12288

    const int n_x  = T_STEPS * BATCH * IN_SZ;   // 16,777,216
    const int n_wi = GATES * IN_SZ;             // 12,582,912
    const int n_wh = GATES * BLK;               //  6,291,456

    cast_f32_bf16<<<(n_x / 4 + 255) / 256, 256, 0, stream>>>(x,  x_bf,  n_x / 4);
    cast_f32_bf16<<<(n_wi / 4 + 255) / 256, 256, 0, stream>>>(Wi, wi_bf, n_wi / 4);
    cast_f32_bf16<<<(n_wh / 4 + 255) / 256, 256, 0, stream>>>(Wh, wh_bf, n_wh / 4);
    init_h<<<(BATCH * HID + 255) / 256, 256, 0, stream>>>(h0, hT, h_bf, BATCH * HID);

    for (int t = 0; t < T_STEPS; t++) {
        gemm_step<<<384, 256, 0, stream>>>(
            x_bf + (size_t)t * BATCH * IN_SZ, h_bf, wi_bf, wh_bf, xgb, hgb);
        pointwise<<<BATCH * HID / 256, 256, 0, stream>>>(
            xgb, hgb, Wib, bh, hT, out + (size_t)t * BATCH * HID, h_bf);
    }
}

// Round 2
// 2113.846 us; speedup vs baseline: 1.8185x; 1.8185x over previous
//
#include <hip/hip_runtime.h>

#define T_STEPS 64
#define BATCH   256
#define IN_SZ   1024
#define HID     4096
#define BLK     512
#define GATES   12288   // 3*HID
#define GROW    1536    // 3*BLK, rows per diagonal block

#define BM 128
#define BN 128
#define BK 64

using bf16x8  = __attribute__((ext_vector_type(8))) __bf16;
using floatx4 = __attribute__((ext_vector_type(4))) float;
typedef const __attribute__((address_space(1))) unsigned int* gas_u32;
typedef __attribute__((address_space(3))) unsigned int* las_u32;

__device__ __forceinline__ unsigned short f2bf(float f) {
    union { float f; unsigned int u; } v; v.f = f;
    unsigned int u = v.u;
    unsigned int r = (u + 0x7fffu + ((u >> 16) & 1u)) >> 16;
    return (unsigned short)r;
}

// ---- fp32 -> bf16 cast (vectorized x4) ----
__global__ __launch_bounds__(256) void cast_f32_bf16(
    const float* __restrict__ in, unsigned short* __restrict__ out, int n4)
{
    int i = blockIdx.x * 256 + threadIdx.x;
    if (i >= n4) return;
    float4 v = reinterpret_cast<const float4*>(in)[i];
    ushort4 o;
    o.x = f2bf(v.x); o.y = f2bf(v.y); o.z = f2bf(v.z); o.w = f2bf(v.w);
    reinterpret_cast<ushort4*>(out)[i] = o;
}

// ---- init h state (fp32 in d_out's h_T region) + bf16 copy ----
__global__ __launch_bounds__(256) void init_h(
    const float* __restrict__ h0, float* __restrict__ hT,
    unsigned short* __restrict__ hbf, int n)
{
    int i = blockIdx.x * 256 + threadIdx.x;
    if (i >= n) return;
    float v = h0[i];
    hT[i] = v;
    hbf[i] = f2bf(v);
}

// ---- m97-style GEMM: C(M,GATES) = A(M,K-slice) . B(GATES,K)^T ----
// 128x128 tile, BK=64, global_load_lds staging, XOR-swizzled LDS layout.
// A row-major lda; B row-major with ldb=K (weight rows). blockdiag selects
// the h-GEMM A-column offset (n0/1536)*512.
// LDS swizzle: 16B chunk stored at (row, p) holds logical col-block p^(row&7).
__global__ __launch_bounds__(256, 2) void gemm_abt(
    const unsigned short* __restrict__ Ag,
    const unsigned short* __restrict__ Bg,
    float* __restrict__ C,
    int lda, int K, int nt_count, int blockdiag)
{
    __shared__ unsigned short lsA[BM * BK];
    __shared__ unsigned short lsB[BN * BK];

    const int bx = blockIdx.x;
    const int mt = bx / nt_count;
    const int nt = bx - mt * nt_count;
    const int m0 = mt * BM;
    const int n0 = nt * BN;

    const int tid  = threadIdx.x;
    const int wave = tid >> 6;
    const int lane = tid & 63;
    const int q    = lane >> 4;
    const int l16  = lane & 15;
    const int wm   = (wave >> 1) * 64;
    const int wn   = (wave & 1) * 64;

    const int a_col0 = blockdiag ? (n0 / GROW) * BLK : 0;

    floatx4 acc[4][4];
    #pragma unroll
    for (int mf = 0; mf < 4; mf++)
        #pragma unroll
        for (int nf = 0; nf < 4; nf++)
            acc[mf][nf] = floatx4{0.0f, 0.0f, 0.0f, 0.0f};

    for (int k0 = 0; k0 < K; k0 += BK) {
        __syncthreads();   // previous iter's ds_reads done before overwrite
        #pragma unroll
        for (int i = 0; i < 4; i++) {
            const int seg = wave * 4 + i;          // 1 KiB segment id
            const int g   = seg * 64 + lane;       // 16B-chunk linear id
            const int row = g >> 3;
            const int cs  = ((g & 7) ^ (row & 7)) << 3;  // swizzled col element
            const unsigned short* ga = Ag + (size_t)(m0 + row) * lda + a_col0 + k0 + cs;
            __builtin_amdgcn_global_load_lds((gas_u32)ga,
                (las_u32)&lsA[seg * 512 + lane * 8], 16, 0, 0);
            const unsigned short* gb = Bg + (size_t)(n0 + row) * (size_t)K + k0 + cs;
            __builtin_amdgcn_global_load_lds((gas_u32)gb,
                (las_u32)&lsB[seg * 512 + lane * 8], 16, 0, 0);
        }
        __syncthreads();   // compiler emits vmcnt(0) drain before barrier

        #pragma unroll
        for (int ks = 0; ks < BK; ks += 32) {
            bf16x8 a[4], b[4];
            #pragma unroll
            for (int mf = 0; mf < 4; mf++) {
                const int row = wm + mf * 16 + l16;
                const int pb  = ((ks >> 3) + q) ^ (row & 7);
                a[mf] = *reinterpret_cast<const bf16x8*>(&lsA[row * BK + pb * 8]);
            }
            #pragma unroll
            for (int nf = 0; nf < 4; nf++) {
                const int row = wn + nf * 16 + l16;
                const int pb  = ((ks >> 3) + q) ^ (row & 7);
                b[nf] = *reinterpret_cast<const bf16x8*>(&lsB[row * BK + pb * 8]);
            }
            #pragma unroll
            for (int mf = 0; mf < 4; mf++)
                #pragma unroll
                for (int nf = 0; nf < 4; nf++)
                    acc[mf][nf] = __builtin_amdgcn_mfma_f32_16x16x32_bf16(
                        a[mf], b[nf], acc[mf][nf], 0, 0, 0);
        }
    }

    // Epilogue: D row(m) = q*4 + reg, col(n) = l16 within each 16x16 frag.
    #pragma unroll
    for (int mf = 0; mf < 4; mf++) {
        const int mrow0 = m0 + wm + mf * 16 + q * 4;
        #pragma unroll
        for (int nf = 0; nf < 4; nf++) {
            const int col = n0 + wn + nf * 16 + l16;
            #pragma unroll
            for (int r = 0; r < 4; r++)
                C[(size_t)(mrow0 + r) * GATES + col] = acc[mf][nf][r];
        }
    }
}

// ---- pointwise GRU update ----
__global__ __launch_bounds__(256) void pointwise(
    const float* __restrict__ xgb, const float* __restrict__ hgb,
    const float* __restrict__ wib, const float* __restrict__ bh,
    float* __restrict__ hT, float* __restrict__ out,
    unsigned short* __restrict__ hbf)
{
    int gid = blockIdx.x * 256 + threadIdx.x;   // 0 .. 1048575
    int b = gid >> 12;
    int i = gid & 4095;
    size_t base = (size_t)b * GATES;

    float g_r  = (xgb[base + i]        + wib[i])        + (hgb[base + i]        + bh[i]);
    float g_z  = (xgb[base + HID + i]  + wib[HID + i])  + (hgb[base + HID + i]  + bh[HID + i]);
    float x_n  =  xgb[base + 2*HID + i] + wib[2*HID + i];
    float h_n  =  hgb[base + 2*HID + i] + bh[2*HID + i];

    float r = 1.0f / (1.0f + __expf(-g_r));
    float z = 1.0f / (1.0f + __expf(-g_z));
    float n = tanhf(x_n + r * h_n);

    size_t hi = (size_t)b * HID + i;
    float h_old = hT[hi];
    float h_new = (1.0f - z) * n + z * h_old;
    hT[hi]  = h_new;
    out[hi] = h_new;
    hbf[hi] = f2bf(h_new);
}

extern "C" void kernel_launch(void* const* d_in, const int* in_sizes, int n_in,
                              void* d_out, int out_size, void* d_ws, size_t ws_size,
                              hipStream_t stream)
{
    const float* x   = (const float*)d_in[0];   // (64,256,1024)
    const float* h0  = (const float*)d_in[1];   // (256,4096)
    const float* Wi  = (const float*)d_in[2];   // (12288,1024)
    const float* Wib = (const float*)d_in[3];   // (12288,)
    const float* Wh  = (const float*)d_in[4];   // (8,1536,512)
    const float* bh  = (const float*)d_in[5];   // (12288,)

    float* out = (float*)d_out;                          // (64,256,4096)
    float* hT  = out + (size_t)T_STEPS * BATCH * HID;    // (256,4096) — live h state

    // workspace layout (~850 MiB of the ~1040 MiB ws)
    float* xg_all        = (float*)d_ws;                                   // 64*256*12288 f32 (805 MB)
    unsigned short* x_bf = (unsigned short*)(xg_all + (size_t)T_STEPS * BATCH * GATES);
    unsigned short* wi_bf = x_bf  + (size_t)T_STEPS * BATCH * IN_SZ;       // 12288*1024
    unsigned short* wh_bf = wi_bf + (size_t)GATES * IN_SZ;                 // 12288*512
    unsigned short* h_bf  = wh_bf + (size_t)GATES * BLK;                   // 256*4096
    float* hgb = (float*)(h_bf + (size_t)BATCH * HID);                     // 256*12288

    const int n_x  = T_STEPS * BATCH * IN_SZ;   // 16,777,216
    const int n_wi = GATES * IN_SZ;             // 12,582,912
    const int n_wh = GATES * BLK;               //  6,291,456

    cast_f32_bf16<<<(n_x / 4 + 255) / 256, 256, 0, stream>>>(x,  x_bf,  n_x / 4);
    cast_f32_bf16<<<(n_wi / 4 + 255) / 256, 256, 0, stream>>>(Wi, wi_bf, n_wi / 4);
    cast_f32_bf16<<<(n_wh / 4 + 255) / 256, 256, 0, stream>>>(Wh, wh_bf, n_wh / 4);
    init_h<<<(BATCH * HID + 255) / 256, 256, 0, stream>>>(h0, hT, h_bf, BATCH * HID);

    // Hoisted x-projection: (16384 x 1024) . (12288 x 1024)^T -> (16384 x 12288)
    gemm_abt<<<(T_STEPS * BATCH / BM) * (GATES / BN), 256, 0, stream>>>(
        x_bf, wi_bf, xg_all, IN_SZ, IN_SZ, GATES / BN, 0);

    for (int t = 0; t < T_STEPS; t++) {
        // h-GEMM: (256 x 512-slice) . (12288 x 512)^T block-diagonal
        gemm_abt<<<(BATCH / BM) * (GATES / BN), 256, 0, stream>>>(
            h_bf, wh_bf, hgb, HID, BLK, GATES / BN, 1);
        pointwise<<<BATCH * HID / 256, 256, 0, stream>>>(
            xg_all + (size_t)t * BATCH * GATES, hgb, Wib, bh,
            hT, out + (size_t)t * BATCH * HID, h_bf);
    }
}